// Round 3
// baseline (199.234 us; speedup 1.0000x reference)
//
#include <hip/hip_runtime.h>
#include <hip/hip_bf16.h>

// Problem constants (from reference)
#define N_NODES 100000
#define FEAT    256
#define HID     128
#define REL     2
#define BATCH   20000
#define KNEI    10

#define APAD    8            // pad shorts per LDS A row (breaks pow-2 stride)
#define AROW    (768 + APAD) // 776 shorts = 1552 B row stride

typedef short bf16x8 __attribute__((ext_vector_type(8)));
typedef float f32x4  __attribute__((ext_vector_type(4)));

__device__ __forceinline__ unsigned short f2bf(float x) {
    union { float f; unsigned u; } v; v.f = x;
    unsigned r = v.u + 0x7fffu + ((v.u >> 16) & 1u);   // RNE
    return (unsigned short)(r >> 16);
}

__device__ __forceinline__ ushort4 pack4(float a, float b, float c, float d) {
    ushort4 p; p.x = f2bf(a); p.y = f2bf(b); p.z = f2bf(c); p.w = f2bf(d);
    return p;
}

// Swizzled B index for logical (k, n):
//   kt=k>>5, j=k&7, hi=(k>>3)&3, lane=hi*16+(n&15), nt=n>>4
//   dest = ((kt*8+nt)*64 + lane)*8 + j
__device__ __forceinline__ size_t bsw_index(int k, int n) {
    int kt = k >> 5, j = k & 7, hi = (k >> 3) & 3;
    int lane = hi * 16 + (n & 15), nt = n >> 4;
    return ((size_t)(kt * 8 + nt) * 64 + lane) * 8 + j;
}

// ---------------------------------------------------------------------------
// prep_B: build collapsed weight into MFMA-swizzled bf16 layout.
//   blocks 0..255  : one f-row per thread-half; 128-deep dot, fully unrolled.
//   blocks 256..271: straight copy of W_det rows 0..255 (coalesced reads).
// ---------------------------------------------------------------------------
__global__ __launch_bounds__(256) void prep_B(const float* __restrict__ W_stc,
                                              const float* __restrict__ W_det,
                                              unsigned short* __restrict__ Bsw) {
    const int blk = blockIdx.x;
    const int tid = threadIdx.x;
    if (blk < 256) {
        const int rel = blk >> 7;                      // 0..1
        const int f   = (blk & 127) * 2 + (tid >> 7);  // 0..255
        const int n   = tid & 127;
        const float* ws = W_stc + (size_t)(rel * FEAT + f) * HID;
        const float* wd = W_det + (size_t)(256 + rel * HID) * HID + n;  // column base
        float acc = 0.f;
        #pragma unroll
        for (int j = 0; j < HID; ++j) acc += ws[j] * wd[(size_t)j * HID];
        Bsw[bsw_index(256 + rel * 256 + f, n)] = f2bf(acc);
    } else {
        const int base = (blk - 256) * 2048;           // 16 blocks x 2048 elems
        #pragma unroll
        for (int i = 0; i < 8; ++i) {
            const int idx = base + i * 256 + tid;      // < 32768
            const int k = idx >> 7, n = idx & 127;
            Bsw[bsw_index(k, n)] = f2bf(W_det[idx]);
        }
    }
}

// ---------------------------------------------------------------------------
// fused: gather+mean into LDS A-tile (bf16), then MFMA GEMM + ReLU.
// One block (4 waves) per 16-row M-tile. 1250 blocks.
//   Phase 0: all 336 block indices staged into LDS via coalesced passes.
//   Phase 1: wave w gathers batch elems m = w*4..w*4+3. All 21 row loads of
//            an element are issued BEFORE a sched_barrier(0) fence; the
//            accumulation sits after it. The fence forces the scheduler to
//            materialize all 21 load destinations (no sinking loads into
//            uses -> ~21 loads in flight per wave instead of ~5; round-2
//            showed VGPR=52, i.e. the un-fenced batch was re-serialized).
//            Loads of elem e+1 live between fence e and fence e+1, so the
//            scheduler may still overlap them with elem e's accumulation.
//   Phase 2: wave w computes n-tiles {w, w+4}: 24 kt x 2 MFMA from LDS A
//            fragments (ds_read_b128) and L2-resident swizzled B.
// ---------------------------------------------------------------------------
__global__ __launch_bounds__(256, 4) void fused(const int* __restrict__ nodes,
                                                const int* __restrict__ neigh_idx,
                                                const float* __restrict__ features,
                                                const unsigned short* __restrict__ Bsw,
                                                float* __restrict__ out) {
    __shared__ unsigned short As[16 * AROW];   // 24832 B
    __shared__ int idxs[336];                  // [0..15] self | [16..175] rel0 | [176..335] rel1

    const int blk  = blockIdx.x;               // m-tile id (0..1249)
    const int tid  = threadIdx.x;
    const int w    = tid >> 6;                 // wave 0..3
    const int lane = tid & 63;
    const float4* F4 = (const float4*)features;
    const float inv = 1.0f / (float)KNEI;

    // ---- Phase 0: stage indices into LDS (coalesced) ----
    {
        if (tid < 16)       idxs[tid] = nodes[blk * 16 + tid];
        else if (tid < 176) idxs[tid] = neigh_idx[blk * 160 + (tid - 16)];
        else                idxs[tid] = neigh_idx[BATCH * KNEI + blk * 160 + (tid - 176)];
        const int t2 = tid + 256;              // [256,336): rel1 tail
        if (t2 < 336)       idxs[t2] = neigh_idx[BATCH * KNEI + blk * 160 + (t2 - 176)];
    }
    __syncthreads();

    // ---- Phase 1: gather + mean, batched loads ----
    #pragma unroll
    for (int e = 0; e < 4; ++e) {
        const int m = w * 4 + e;               // row in tile

        // indices first (LDS reads batch together)
        int ia[11], ib[10];
        ia[0] = idxs[m];
        #pragma unroll
        for (int k = 0; k < KNEI; ++k) ia[1 + k] = idxs[16 + m * KNEI + k];
        #pragma unroll
        for (int k = 0; k < KNEI; ++k) ib[k]     = idxs[176 + m * KNEI + k];

        // issue all 21 row loads
        float4 ta[11];                         // self + rel0 neighbors
        #pragma unroll
        for (int k = 0; k < 11; ++k)
            ta[k] = F4[(size_t)ia[k] * 64 + lane];
        float4 tb[10];                         // rel1 neighbors
        #pragma unroll
        for (int k = 0; k < KNEI; ++k)
            tb[k] = F4[(size_t)ib[k] * 64 + lane];

        // fence: nothing crosses -> all 21 loads issued before any use
        __builtin_amdgcn_sched_barrier(0);

        // serial accumulation in original k-order (preserves prior numerics)
        float4 s0 = ta[1];
        #pragma unroll
        for (int k = 1; k < KNEI; ++k) {
            s0.x += ta[1 + k].x; s0.y += ta[1 + k].y;
            s0.z += ta[1 + k].z; s0.w += ta[1 + k].w;
        }
        float4 s1 = tb[0];
        #pragma unroll
        for (int k = 1; k < KNEI; ++k) {
            s1.x += tb[k].x; s1.y += tb[k].y;
            s1.z += tb[k].z; s1.w += tb[k].w;
        }

        ushort4* row = (ushort4*)(As + m * AROW);
        row[lane]       = pack4(ta[0].x, ta[0].y, ta[0].z, ta[0].w);
        row[64 + lane]  = pack4(s0.x * inv, s0.y * inv, s0.z * inv, s0.w * inv);
        row[128 + lane] = pack4(s1.x * inv, s1.y * inv, s1.z * inv, s1.w * inv);
    }
    __syncthreads();

    // ---- Phase 2: GEMM + ReLU ----
    const int quad = lane >> 4;
    const int l16  = lane & 15;
    const unsigned short* a_base = As + l16 * AROW + quad * 8;

    f32x4 acc0 = (f32x4){0.f, 0.f, 0.f, 0.f};
    f32x4 acc1 = (f32x4){0.f, 0.f, 0.f, 0.f};
    const int nt0 = w, nt1 = w + 4;

    #pragma unroll
    for (int kt = 0; kt < 24; ++kt) {
        bf16x8 a = *(const bf16x8*)(a_base + kt * 32);
        const unsigned short* bk = Bsw + ((size_t)(kt * 8) * 64 + lane) * 8;
        bf16x8 b0 = *(const bf16x8*)(bk + (size_t)nt0 * 64 * 8);
        bf16x8 b1 = *(const bf16x8*)(bk + (size_t)nt1 * 64 * 8);
        acc0 = __builtin_amdgcn_mfma_f32_16x16x32_bf16(a, b0, acc0, 0, 0, 0);
        acc1 = __builtin_amdgcn_mfma_f32_16x16x32_bf16(a, b1, acc1, 0, 0, 0);
    }

    float* orow = out + (size_t)(blk * 16) * HID;
    #pragma unroll
    for (int r = 0; r < 4; ++r) {
        const int row = quad * 4 + r;
        float v0 = acc0[r];
        float v1 = acc1[r];
        orow[(size_t)row * HID + nt0 * 16 + l16] = v0 > 0.f ? v0 : 0.f;
        orow[(size_t)row * HID + nt1 * 16 + l16] = v1 > 0.f ? v1 : 0.f;
    }
}

extern "C" void kernel_launch(void* const* d_in, const int* in_sizes, int n_in,
                              void* d_out, int out_size, void* d_ws, size_t ws_size,
                              hipStream_t stream) {
    const int*   nodes     = (const int*)d_in[0];
    const int*   neigh_idx = (const int*)d_in[1];
    const float* features  = (const float*)d_in[2];
    const float* W_stc     = (const float*)d_in[3];
    const float* W_det     = (const float*)d_in[4];
    float* out = (float*)d_out;

    unsigned short* Bsw = (unsigned short*)d_ws;   // 768*128 bf16 = 192 KB

    prep_B<<<272, 256, 0, stream>>>(W_stc, W_det, Bsw);
    fused<<<BATCH / 16, 256, 0, stream>>>(nodes, neigh_idx, features, Bsw, out);
}

// Round 4
// 197.712 us; speedup vs baseline: 1.0077x; 1.0077x over previous
//
#include <hip/hip_runtime.h>
#include <hip/hip_bf16.h>

// Problem constants (from reference)
#define N_NODES 100000
#define FEAT    256
#define HID     128
#define REL     2
#define BATCH   20000
#define KNEI    10

#define APAD    8            // pad shorts per LDS A row (breaks pow-2 stride)
#define AROW    (768 + APAD) // 776 shorts = 1552 B row stride

typedef short bf16x8 __attribute__((ext_vector_type(8)));
typedef float f32x4  __attribute__((ext_vector_type(4)));

__device__ __forceinline__ unsigned short f2bf(float x) {
    union { float f; unsigned u; } v; v.f = x;
    unsigned r = v.u + 0x7fffu + ((v.u >> 16) & 1u);   // RNE
    return (unsigned short)(r >> 16);
}

__device__ __forceinline__ ushort4 pack4(float a, float b, float c, float d) {
    ushort4 p; p.x = f2bf(a); p.y = f2bf(b); p.z = f2bf(c); p.w = f2bf(d);
    return p;
}

// Swizzled B index for logical (k, n):
//   kt=k>>5, j=k&7, hi=(k>>3)&3, lane=hi*16+(n&15), nt=n>>4
//   dest = ((kt*8+nt)*64 + lane)*8 + j
__device__ __forceinline__ size_t bsw_index(int k, int n) {
    int kt = k >> 5, j = k & 7, hi = (k >> 3) & 3;
    int lane = hi * 16 + (n & 15), nt = n >> 4;
    return ((size_t)(kt * 8 + nt) * 64 + lane) * 8 + j;
}

// ---------------------------------------------------------------------------
// prep_B: build collapsed weight into MFMA-swizzled bf16 layout.
//   blocks 0..255  : one f-row per thread-half; 128-deep dot, fully unrolled.
//   blocks 256..271: straight copy of W_det rows 0..255 (coalesced reads).
// ---------------------------------------------------------------------------
__global__ __launch_bounds__(256) void prep_B(const float* __restrict__ W_stc,
                                              const float* __restrict__ W_det,
                                              unsigned short* __restrict__ Bsw) {
    const int blk = blockIdx.x;
    const int tid = threadIdx.x;
    if (blk < 256) {
        const int rel = blk >> 7;                      // 0..1
        const int f   = (blk & 127) * 2 + (tid >> 7);  // 0..255
        const int n   = tid & 127;
        const float* ws = W_stc + (size_t)(rel * FEAT + f) * HID;
        const float* wd = W_det + (size_t)(256 + rel * HID) * HID + n;  // column base
        float acc = 0.f;
        #pragma unroll
        for (int j = 0; j < HID; ++j) acc += ws[j] * wd[(size_t)j * HID];
        Bsw[bsw_index(256 + rel * 256 + f, n)] = f2bf(acc);
    } else {
        const int base = (blk - 256) * 2048;           // 16 blocks x 2048 elems
        #pragma unroll
        for (int i = 0; i < 8; ++i) {
            const int idx = base + i * 256 + tid;      // < 32768
            const int k = idx >> 7, n = idx & 127;
            Bsw[bsw_index(k, n)] = f2bf(W_det[idx]);
        }
    }
}

// ---------------------------------------------------------------------------
// fused: gather+mean into LDS A-tile (bf16), then MFMA GEMM + ReLU.
// One block (4 waves) per 16-row M-tile. 1250 blocks.
//   Phase 0: all 336 block indices staged into LDS via coalesced passes.
//   Phase 1: wave w gathers batch elems m = w*4..w*4+3. The 21 row loads of
//            an element are emitted as volatile inline-asm global_load_dwordx4
//            (saddr form: SGPR base + 32-bit lane offset). Volatile asm order
//            + distinct "=v" outputs FORCE 21 loads in flight per wave —
//            rounds 1-3 proved the compiler re-serializes plain-HIP batches
//            (VGPR stuck at 52). Manual s_waitcnt: vmcnt(10) -> rel0 done,
//            accumulate while rel1's 10 loads fly; vmcnt(0) -> rel1 done.
//            sched_barrier(0) after each waitcnt (rule: compiler hoists
//            register-only consumers past inline-asm waitcnt otherwise).
//   Phase 2: wave w computes n-tiles {w, w+4}: 24 kt x 2 MFMA from LDS A
//            fragments (ds_read_b128) and L2-resident swizzled B.
// ---------------------------------------------------------------------------
__global__ __launch_bounds__(256, 4) void fused(const int* __restrict__ nodes,
                                                const int* __restrict__ neigh_idx,
                                                const float* __restrict__ features,
                                                const unsigned short* __restrict__ Bsw,
                                                float* __restrict__ out) {
    __shared__ unsigned short As[16 * AROW];   // 24832 B
    __shared__ int idxs[336];                  // [0..15] self | [16..175] rel0 | [176..335] rel1

    const int blk  = blockIdx.x;               // m-tile id (0..1249)
    const int tid  = threadIdx.x;
    const int w    = tid >> 6;                 // wave 0..3
    const int lane = tid & 63;
    const float inv = 1.0f / (float)KNEI;

    // ---- Phase 0: stage indices into LDS (coalesced) ----
    {
        if (tid < 16)       idxs[tid] = nodes[blk * 16 + tid];
        else if (tid < 176) idxs[tid] = neigh_idx[blk * 160 + (tid - 16)];
        else                idxs[tid] = neigh_idx[BATCH * KNEI + blk * 160 + (tid - 176)];
        const int t2 = tid + 256;              // [256,336): rel1 tail
        if (t2 < 336)       idxs[t2] = neigh_idx[BATCH * KNEI + blk * 160 + (t2 - 176)];
    }
    __syncthreads();

    // ---- Phase 1: gather + mean, forced-MLP loads ----
    const unsigned lnoff = (unsigned)lane << 4;          // lane byte offset in row
    #pragma unroll
    for (int e = 0; e < 4; ++e) {
        const int m = w * 4 + e;               // row in tile

        int ia[11], ib[10];
        ia[0] = idxs[m];
        #pragma unroll
        for (int k = 0; k < KNEI; ++k) ia[1 + k] = idxs[16 + m * KNEI + k];
        #pragma unroll
        for (int k = 0; k < KNEI; ++k) ib[k]     = idxs[176 + m * KNEI + k];

        // issue all 21 row loads; volatile asm pins issue order, distinct
        // outputs pin 84 live VGPRs -> real MLP=21.
        f32x4 ta[11];                          // self + rel0 neighbors
        #pragma unroll
        for (int k = 0; k < 11; ++k) {
            const unsigned voff = ((unsigned)ia[k] << 10) + lnoff;  // idx*1024 + lane*16
            asm volatile("global_load_dwordx4 %0, %1, %2"
                         : "=v"(ta[k]) : "v"(voff), "s"(features));
        }
        f32x4 tb[10];                          // rel1 neighbors
        #pragma unroll
        for (int k = 0; k < KNEI; ++k) {
            const unsigned voff = ((unsigned)ib[k] << 10) + lnoff;
            asm volatile("global_load_dwordx4 %0, %1, %2"
                         : "=v"(tb[k]) : "v"(voff), "s"(features));
        }

        // all 11 ta landed; 10 tb still in flight
        asm volatile("s_waitcnt vmcnt(10)" ::: "memory");
        __builtin_amdgcn_sched_barrier(0);

        f32x4 s0 = ta[1];
        #pragma unroll
        for (int k = 2; k < 11; ++k) s0 += ta[k];

        ushort4* row = (ushort4*)(As + m * AROW);
        row[lane]      = pack4(ta[0][0], ta[0][1], ta[0][2], ta[0][3]);
        row[64 + lane] = pack4(s0[0] * inv, s0[1] * inv, s0[2] * inv, s0[3] * inv);

        asm volatile("s_waitcnt vmcnt(0)" ::: "memory");
        __builtin_amdgcn_sched_barrier(0);

        f32x4 s1 = tb[0];
        #pragma unroll
        for (int k = 1; k < KNEI; ++k) s1 += tb[k];
        row[128 + lane] = pack4(s1[0] * inv, s1[1] * inv, s1[2] * inv, s1[3] * inv);
    }
    __syncthreads();

    // ---- Phase 2: GEMM + ReLU ----
    const int quad = lane >> 4;
    const int l16  = lane & 15;
    const unsigned short* a_base = As + l16 * AROW + quad * 8;

    f32x4 acc0 = (f32x4){0.f, 0.f, 0.f, 0.f};
    f32x4 acc1 = (f32x4){0.f, 0.f, 0.f, 0.f};
    const int nt0 = w, nt1 = w + 4;

    #pragma unroll
    for (int kt = 0; kt < 24; ++kt) {
        bf16x8 a = *(const bf16x8*)(a_base + kt * 32);
        const unsigned short* bk = Bsw + ((size_t)(kt * 8) * 64 + lane) * 8;
        bf16x8 b0 = *(const bf16x8*)(bk + (size_t)nt0 * 64 * 8);
        bf16x8 b1 = *(const bf16x8*)(bk + (size_t)nt1 * 64 * 8);
        acc0 = __builtin_amdgcn_mfma_f32_16x16x32_bf16(a, b0, acc0, 0, 0, 0);
        acc1 = __builtin_amdgcn_mfma_f32_16x16x32_bf16(a, b1, acc1, 0, 0, 0);
    }

    float* orow = out + (size_t)(blk * 16) * HID;
    #pragma unroll
    for (int r = 0; r < 4; ++r) {
        const int row = quad * 4 + r;
        float v0 = acc0[r];
        float v1 = acc1[r];
        orow[(size_t)row * HID + nt0 * 16 + l16] = v0 > 0.f ? v0 : 0.f;
        orow[(size_t)row * HID + nt1 * 16 + l16] = v1 > 0.f ? v1 : 0.f;
    }
}

extern "C" void kernel_launch(void* const* d_in, const int* in_sizes, int n_in,
                              void* d_out, int out_size, void* d_ws, size_t ws_size,
                              hipStream_t stream) {
    const int*   nodes     = (const int*)d_in[0];
    const int*   neigh_idx = (const int*)d_in[1];
    const float* features  = (const float*)d_in[2];
    const float* W_stc     = (const float*)d_in[3];
    const float* W_det     = (const float*)d_in[4];
    float* out = (float*)d_out;

    unsigned short* Bsw = (unsigned short*)d_ws;   // 768*128 bf16 = 192 KB

    prep_B<<<272, 256, 0, stream>>>(W_stc, W_det, Bsw);
    fused<<<BATCH / 16, 256, 0, stream>>>(nodes, neigh_idx, features, Bsw, out);
}